// Round 5
// baseline (276.869 us; speedup 1.0000x reference)
//
#include <hip/hip_runtime.h>
#include <hip/hip_bf16.h>

typedef __bf16 bf16x8 __attribute__((ext_vector_type(8)));
typedef __bf16 bf16x4 __attribute__((ext_vector_type(4)));
typedef float  f32x4  __attribute__((ext_vector_type(4)));

#define MFMA16(a, b, c) __builtin_amdgcn_mfma_f32_16x16x32_bf16(a, b, c, 0, 0, 0)

__device__ __forceinline__ float lrelu(float v) { return fmaxf(v, 0.01f * v); }

// ---------------------------------------------------------------------------
// prep kernels
// ---------------------------------------------------------------------------

// w1s[f][h] = sum_i linear1_w[f][i][h]   (16384 elements)
__global__ void vg_w1s(const float* __restrict__ lw1, float* __restrict__ w1s) {
  int i = blockIdx.x * 256 + threadIdx.x;
  int f = i >> 6, h = i & 63;
  w1s[i] = lw1[f * 192 + h] + lw1[f * 192 + 64 + h] + lw1[f * 192 + 128 + h];
}

// W2T[f][n(16,pad)][k(64)] = bf16(linear2_w[f][k][n]) , n>=8 -> 0   (262144)
__global__ void vg_w2t(const float* __restrict__ lw2, __bf16* __restrict__ w2t) {
  int i = blockIdx.x * 256 + threadIdx.x;
  int f = i >> 10, n = (i >> 6) & 15, k = i & 63;
  float v = (n < 8) ? lw2[(f * 64 + k) * 8 + n] : 0.f;
  w2t[i] = (__bf16)v;
}

// embT[f][d(128)][k(32,pad)] = bf16(emb[f][k][d]) , k>=8 -> 0   (1048576)
__global__ void vg_embt(const float* __restrict__ emb, __bf16* __restrict__ embt) {
  int i = blockIdx.x * 256 + threadIdx.x;
  int f = i >> 12, d = (i >> 5) & 127, k = i & 31;
  float v = (k < 8) ? emb[(f * 8 + k) * 128 + d] : 0.f;
  embt[i] = (__bf16)v;
}

// w1tf[f][n(256)][k(128)] = bf16(pw1[(f*128+k)*256 + n])  -- per-f contiguous
__global__ void vg_w1tf(const float* __restrict__ pw1, __bf16* __restrict__ w1tf) {
  __shared__ __bf16 tl[128][258];
  const int f = blockIdx.x, t = threadIdx.x;
  const float* src = pw1 + (size_t)f * 32768;
  for (int idx = t; idx < 32768; idx += 256) {
    int k = idx >> 8, n = idx & 255;
    tl[k][n] = (__bf16)src[idx];
  }
  __syncthreads();
  __bf16* dst = w1tf + (size_t)f * 32768;
  for (int idx = t; idx < 32768; idx += 256) {
    int n = idx >> 7, k = idx & 127;
    dst[idx] = tl[k][n];
  }
}

// transpose [R][C] f32 -> [C][R] bf16, 64x64 LDS tiles (for proj_w2)
__global__ void vg_transpose(const float* __restrict__ in, __bf16* __restrict__ outT,
                             int R, int C) {
  __shared__ float tile[64][65];
  int tilesPerRow = C >> 6;
  int tr = blockIdx.x / tilesPerRow, tc = blockIdx.x % tilesPerRow;
  int r0 = tr * 64, c0 = tc * 64;
  int t = threadIdx.x;
  int cc = t & 63, rq = t >> 6;
#pragma unroll 4
  for (int i = 0; i < 16; i++) {
    int rr = rq * 16 + i;
    tile[rr][cc] = in[(size_t)(r0 + rr) * C + c0 + cc];
  }
  __syncthreads();
  int rr2 = t & 63, cq = t >> 6;
#pragma unroll 4
  for (int i = 0; i < 16; i++) {
    int cc2 = cq * 16 + i;
    outT[(size_t)(c0 + cc2) * R + r0 + rr2] = (__bf16)tile[rr2][cc2];
  }
}

// ---------------------------------------------------------------------------
// main fused kernel: per block = 64 rows x one f-group (32 f's)
// role-specialized waves: w0-3 consumers (phase 4), w4-7 producers (phases 1-3)
// produces zpart[g][4096][256] f32
// ---------------------------------------------------------------------------
__global__ __launch_bounds__(512, 4) void vg_main(
    const float* __restrict__ x,      // [4096][256]
    const float* __restrict__ w1s,    // [256][64]
    const float* __restrict__ b1,     // [256][64]
    const __bf16* __restrict__ w2t,   // [256][16][64]
    const float* __restrict__ b2l,    // [256][8]
    const float* __restrict__ tau,    // [256][8]
    const __bf16* __restrict__ embt,  // [256][128][32]
    const __bf16* __restrict__ w1tf,  // [256][256][128]
    float* __restrict__ zpart)        // [8][4096][256]
{
  __shared__ __align__(16) __bf16 elds[2][64 * 128];  // 16B-XOR swizzled, 16KB each
  __shared__ __align__(16) float xs[64][33];
  __shared__ __align__(16) float ws1[2048], wb1[2048];
  __shared__ __align__(16) float wb2[256], wtau[256];

  const int g = blockIdx.x & 7;          // == XCD id (round-robin dispatch)
  const int r0 = (blockIdx.x >> 3) * 64;
  const int f0 = g * 32;
  const int t = threadIdx.x;
  const int w = t >> 6, l = t & 63, lo = l & 15, hi = l >> 4;
  const int team = w >> 2, pw = w & 3;   // team1 = producer, team0 = consumer

  // ---- block init: x tile + per-f params into LDS
  for (int i = t; i < 2048; i += 512) {
    int rr = i >> 5, cc = i & 31;
    float v = x[(size_t)(r0 + rr) * 256 + f0 + cc];
    v = (v != v) ? 0.f : v;
    xs[rr][cc] = fminf(fmaxf(v, 0.f), 65536.f);
  }
  for (int i = t; i < 2048; i += 512) {
    ws1[i] = w1s[f0 * 64 + i];
    wb1[i] = b1[f0 * 64 + i];
  }
  if (t < 256) {
    wb2[t] = b2l[f0 * 8 + t];
    wtau[t] = tau[f0 * 8 + t];
  }
  __syncthreads();  // init visible before prologue produce

  // ---- producer: phases 1-3 for local f-index fi, writing elds[bsel]
  auto produce = [&](int fi, int bsel) {
    const int f = f0 + fi;
    const int row = pw * 16 + lo;

    // phase 1: h B-fragments (n=row, k = s*32+hi*8+j)
    const float xr = xs[row][fi];
    bf16x8 ha[2];
#pragma unroll
    for (int s = 0; s < 2; s++) {
      float4 wa = *(const float4*)(ws1 + fi * 64 + s * 32 + hi * 8);
      float4 wb = *(const float4*)(ws1 + fi * 64 + s * 32 + hi * 8 + 4);
      float4 ba = *(const float4*)(wb1 + fi * 64 + s * 32 + hi * 8);
      float4 bb = *(const float4*)(wb1 + fi * 64 + s * 32 + hi * 8 + 4);
      float hv[8];
      hv[0] = lrelu(xr * wa.x + ba.x);
      hv[1] = lrelu(xr * wa.y + ba.y);
      hv[2] = lrelu(xr * wa.z + ba.z);
      hv[3] = lrelu(xr * wa.w + ba.w);
      hv[4] = lrelu(xr * wb.x + bb.x);
      hv[5] = lrelu(xr * wb.y + bb.y);
      hv[6] = lrelu(xr * wb.z + bb.z);
      hv[7] = lrelu(xr * wb.w + bb.w);
#pragma unroll
      for (int j = 0; j < 8; j++) ha[s][j] = (__bf16)hv[j];
    }

    // phase 2 (swapped): g^T = MFMA(A=w2frag, B=ha)
    f32x4 gacc = {0.f, 0.f, 0.f, 0.f};
#pragma unroll
    for (int s = 0; s < 2; s++) {
      bf16x8 bw = *(const bf16x8*)&w2t[(f * 16 + lo) * 64 + s * 32 + hi * 8];
      gacc = MFMA16(bw, ha[s], gacc);
    }
    // softmax fully in-register: buckets hi*4+{0..3} local, partner via xor16
    const int bidx = fi * 8 + (hi & 1) * 4;
    float4 b2v = *(const float4*)&wb2[bidx];
    float4 tv = *(const float4*)&wtau[bidx];
    float gb[4];
#pragma unroll
    for (int r = 0; r < 4; r++) gb[r] = lrelu(gacc[r] + b2v[r]) * tv[r];
    float m01 = fmaxf(fmaxf(gb[0], gb[1]), fmaxf(gb[2], gb[3]));
    float mx = fmaxf(m01, __shfl_xor(m01, 16));
    float ev[4];
#pragma unroll
    for (int r = 0; r < 4; r++) ev[r] = __expf(gb[r] - mx);
    float s4 = (ev[0] + ev[1]) + (ev[2] + ev[3]);
    s4 += __shfl_xor(s4, 16);
    float inv = __builtin_amdgcn_rcpf(s4);
    float pv[4], ov[4];
#pragma unroll
    for (int r = 0; r < 4; r++) pv[r] = ev[r] * inv;
#pragma unroll
    for (int r = 0; r < 4; r++) ov[r] = __shfl_xor(pv[r], 16);
    const bool keep = (hi == 0);  // K-pad: only k=0..7 nonzero
    bf16x8 pa;
#pragma unroll
    for (int r = 0; r < 4; r++) {
      pa[r] = (__bf16)(keep ? pv[r] : 0.f);
      pa[4 + r] = (__bf16)(keep ? ov[r] : 0.f);
    }

    // phase 3 (swapped): e^T frags = MFMA(A=embt, B=pa) -> ds_write_b64
    const __bf16* ep = embt + (size_t)f * 4096;
    char* ebuf = (char*)&elds[bsel][0];
    const int swz = (row & 7) << 4;
    const int rbase = row * 256;
#pragma unroll
    for (int dblk = 0; dblk < 8; dblk++) {
      bf16x8 ebg = *(const bf16x8*)&ep[(dblk * 16 + lo) * 32 + hi * 8];
      f32x4 cz = {0.f, 0.f, 0.f, 0.f};
      f32x4 ef = MFMA16(ebg, pa, cz);
      bf16x4 pk;
#pragma unroll
      for (int r = 0; r < 4; r++) pk[r] = (__bf16)ef[r];
      *(bf16x4*)(ebuf + rbase + ((dblk * 32 + hi * 8) ^ swz)) = pk;
    }
  };

  // ---- prologue: producers make f-index 0 into buffer 0
  if (team == 1) produce(0, 0);
  __syncthreads();

  f32x4 acc[4][4] = {};

  for (int i = 0; i < 32; i++) {
    const int cur = i & 1;
    if (team == 1) {
      if (i < 31) produce(i + 1, cur ^ 1);
    } else {
      // ---- phase 4 (consumers only): z += e_tile(f0+i) @ W1T
      // wave = all 64 rows x 64 cols (cols w*64 .. w*64+63)
      const __bf16* bp = w1tf + ((size_t)(f0 + i) * 256 + w * 64) * 128;
      const char* abase = (const char*)&elds[cur][0];
#pragma unroll
      for (int ks = 0; ks < 4; ks++) {
        bf16x8 Bq[4];
#pragma unroll
        for (int n = 0; n < 4; n++)
          Bq[n] = *(const bf16x8*)&bp[(n * 16 + lo) * 128 + ks * 32 + hi * 8];
        bf16x8 A[4];
#pragma unroll
        for (int m = 0; m < 4; m++) {
          int row = m * 16 + lo;
          A[m] = *(const bf16x8*)(abase + row * 256 +
                                  ((ks * 64 + hi * 16) ^ ((row & 7) << 4)));
        }
#pragma unroll
        for (int m = 0; m < 4; m++)
#pragma unroll
          for (int n = 0; n < 4; n++) acc[m][n] = MFMA16(A[m], Bq[n], acc[m][n]);
      }
    }
    __syncthreads();
  }

  if (team == 0) {
    float* zp = zpart + (size_t)g * (4096 * 256) + (size_t)r0 * 256;
#pragma unroll
    for (int m = 0; m < 4; m++)
#pragma unroll
      for (int n = 0; n < 4; n++)
#pragma unroll
        for (int r = 0; r < 4; r++) {
          int row = m * 16 + hi * 4 + r;
          int col = w * 64 + n * 16 + lo;
          zp[row * 256 + col] = acc[m][n][r];
        }
  }
}

// ---------------------------------------------------------------------------
// z[b][n] = bf16(relu(sum_g zpart + b1p[n]))  (x4 vectorized)
// ---------------------------------------------------------------------------
__global__ void vg_zred(const float* __restrict__ zpart, const float* __restrict__ b1p,
                        __bf16* __restrict__ z) {
  int i4 = (blockIdx.x * 256 + threadIdx.x) * 4;  // 1048576 total
  float4 s = *(const float4*)&b1p[i4 & 255];
#pragma unroll
  for (int g = 0; g < 8; g++) {
    float4 v = *(const float4*)&zpart[(size_t)g * 1048576 + i4];
    s.x += v.x; s.y += v.y; s.z += v.z; s.w += v.w;
  }
  bf16x4 o;
  o[0] = (__bf16)fmaxf(s.x, 0.f);
  o[1] = (__bf16)fmaxf(s.y, 0.f);
  o[2] = (__bf16)fmaxf(s.z, 0.f);
  o[3] = (__bf16)fmaxf(s.w, 0.f);
  *(bf16x4*)&z[i4] = o;
}

// ---------------------------------------------------------------------------
// out = z @ W2 + b2   (M=4096, N=4096, K=256)
// ---------------------------------------------------------------------------
__global__ __launch_bounds__(256, 2) void vg_out(
    const __bf16* __restrict__ z,    // [4096][256]
    const __bf16* __restrict__ w2t,  // [4096][256]  (W2T[n][k])
    const float* __restrict__ b2,    // [4096]
    float* __restrict__ out)         // [4096][4096]
{
  const int m0 = (blockIdx.x & 31) * 128;
  const int n0 = (blockIdx.x >> 5) * 128;
  const int t = threadIdx.x, w = t >> 6, l = t & 63, lo = l & 15, hi = l >> 4;
  const int wm = w >> 1, wn = w & 1;  // 2x2 waves, 64x64 each
  f32x4 acc[4][4] = {};
#pragma unroll
  for (int ks = 0; ks < 8; ks++) {
    bf16x8 A[4], Bq[4];
#pragma unroll
    for (int m = 0; m < 4; m++)
      A[m] = *(const bf16x8*)&z[(size_t)(m0 + wm * 64 + m * 16 + lo) * 256 + ks * 32 + hi * 8];
#pragma unroll
    for (int n = 0; n < 4; n++)
      Bq[n] = *(const bf16x8*)&w2t[(size_t)(n0 + wn * 64 + n * 16 + lo) * 256 + ks * 32 + hi * 8];
#pragma unroll
    for (int m = 0; m < 4; m++)
#pragma unroll
      for (int n = 0; n < 4; n++) acc[m][n] = MFMA16(A[m], Bq[n], acc[m][n]);
  }
#pragma unroll
  for (int m = 0; m < 4; m++)
#pragma unroll
    for (int n = 0; n < 4; n++) {
      int col = n0 + wn * 64 + n * 16 + lo;
      float bv = b2[col];
#pragma unroll
      for (int r = 0; r < 4; r++) {
        int row = m0 + wm * 64 + m * 16 + hi * 4 + r;
        out[(size_t)row * 4096 + col] = acc[m][n][r] + bv;
      }
    }
}

// ---------------------------------------------------------------------------
extern "C" void kernel_launch(void* const* d_in, const int* in_sizes, int n_in,
                              void* d_out, int out_size, void* d_ws, size_t ws_size,
                              hipStream_t stream) {
  const float* x   = (const float*)d_in[0];
  const float* lw1 = (const float*)d_in[1];
  const float* b1  = (const float*)d_in[2];
  const float* lw2 = (const float*)d_in[3];
  const float* b2l = (const float*)d_in[4];
  const float* tau = (const float*)d_in[5];
  const float* emb = (const float*)d_in[6];
  const float* pw1 = (const float*)d_in[7];
  const float* pb1 = (const float*)d_in[8];
  const float* pw2 = (const float*)d_in[9];
  const float* pb2 = (const float*)d_in[10];
  float* out = (float*)d_out;

  char* ws = (char*)d_ws;
  float*  w1s  = (float*)(ws + 0);          //      65536 B
  __bf16* w2t  = (__bf16*)(ws + 65536);     //     524288 B
  __bf16* embt = (__bf16*)(ws + 589824);    //    2097152 B
  __bf16* w1tf = (__bf16*)(ws + 2686976);   //   16777216 B
  __bf16* w2t3 = (__bf16*)(ws + 19464192);  //    2097152 B
  __bf16* z    = (__bf16*)(ws + 21561344);  //    2097152 B
  float*  zpart = (float*)(ws + 23658496);  //   33554432 B  (total 57212928)

  vg_w1s<<<64, 256, 0, stream>>>(lw1, w1s);
  vg_w2t<<<1024, 256, 0, stream>>>(lw2, w2t);
  vg_embt<<<4096, 256, 0, stream>>>(emb, embt);
  vg_w1tf<<<256, 256, 0, stream>>>(pw1, w1tf);
  vg_transpose<<<256, 256, 0, stream>>>(pw2, w2t3, 256, 4096);
  vg_main<<<512, 512, 0, stream>>>(x, w1s, b1, w2t, b2l, tau, embt, w1tf, zpart);
  vg_zred<<<1024, 256, 0, stream>>>(zpart, pb1, z);
  vg_out<<<1024, 256, 0, stream>>>(z, w2t3, pb2, out);
}

// Round 6
// 244.435 us; speedup vs baseline: 1.1327x; 1.1327x over previous
//
#include <hip/hip_runtime.h>
#include <hip/hip_bf16.h>

typedef __bf16 bf16x8 __attribute__((ext_vector_type(8)));
typedef __bf16 bf16x4 __attribute__((ext_vector_type(4)));
typedef float  f32x4  __attribute__((ext_vector_type(4)));

#define MFMA16(a, b, c) __builtin_amdgcn_mfma_f32_16x16x32_bf16(a, b, c, 0, 0, 0)

__device__ __forceinline__ float lrelu(float v) { return fmaxf(v, 0.01f * v); }

// ---------------------------------------------------------------------------
// prep kernels
// ---------------------------------------------------------------------------

// w1s[f][h] = sum_i linear1_w[f][i][h]   (16384 elements)
__global__ void vg_w1s(const float* __restrict__ lw1, float* __restrict__ w1s) {
  int i = blockIdx.x * 256 + threadIdx.x;
  int f = i >> 6, h = i & 63;
  w1s[i] = lw1[f * 192 + h] + lw1[f * 192 + 64 + h] + lw1[f * 192 + 128 + h];
}

// W2T[f][n(16,pad)][k(64)] = bf16(linear2_w[f][k][n]) , n>=8 -> 0   (262144)
__global__ void vg_w2t(const float* __restrict__ lw2, __bf16* __restrict__ w2t) {
  int i = blockIdx.x * 256 + threadIdx.x;
  int f = i >> 10, n = (i >> 6) & 15, k = i & 63;
  float v = (n < 8) ? lw2[(f * 64 + k) * 8 + n] : 0.f;
  w2t[i] = (__bf16)v;
}

// embT[f][d(128)][k(32,pad)] = bf16(emb[f][k][d]) , k>=8 -> 0   (1048576)
__global__ void vg_embt(const float* __restrict__ emb, __bf16* __restrict__ embt) {
  int i = blockIdx.x * 256 + threadIdx.x;
  int f = i >> 12, d = (i >> 5) & 127, k = i & 31;
  float v = (k < 8) ? emb[(f * 8 + k) * 128 + d] : 0.f;
  embt[i] = (__bf16)v;
}

// w1tf[f][n(256)][k(128)] = bf16(pw1[(f*128+k)*256 + n])  -- per-f contiguous
__global__ void vg_w1tf(const float* __restrict__ pw1, __bf16* __restrict__ w1tf) {
  __shared__ __bf16 tl[128][258];
  const int f = blockIdx.x, t = threadIdx.x;
  const float* src = pw1 + (size_t)f * 32768;
  for (int idx = t; idx < 32768; idx += 256) {
    int k = idx >> 8, n = idx & 255;
    tl[k][n] = (__bf16)src[idx];
  }
  __syncthreads();
  __bf16* dst = w1tf + (size_t)f * 32768;
  for (int idx = t; idx < 32768; idx += 256) {
    int n = idx >> 7, k = idx & 127;
    dst[idx] = tl[k][n];
  }
}

// transpose [R][C] f32 -> [C][R] bf16, 64x64 LDS tiles (for proj_w2)
__global__ void vg_transpose(const float* __restrict__ in, __bf16* __restrict__ outT,
                             int R, int C) {
  __shared__ float tile[64][65];
  int tilesPerRow = C >> 6;
  int tr = blockIdx.x / tilesPerRow, tc = blockIdx.x % tilesPerRow;
  int r0 = tr * 64, c0 = tc * 64;
  int t = threadIdx.x;
  int cc = t & 63, rq = t >> 6;
#pragma unroll 4
  for (int i = 0; i < 16; i++) {
    int rr = rq * 16 + i;
    tile[rr][cc] = in[(size_t)(r0 + rr) * C + c0 + cc];
  }
  __syncthreads();
  int rr2 = t & 63, cq = t >> 6;
#pragma unroll 4
  for (int i = 0; i < 16; i++) {
    int cc2 = cq * 16 + i;
    outT[(size_t)(c0 + cc2) * R + r0 + rr2] = (__bf16)tile[rr2][cc2];
  }
}

// ---------------------------------------------------------------------------
// main fused kernel: per block = 128 rows x one f-group (32 f's)
// 8 waves, each: produce 16 rows of e(f+1)  +  consume 64x64 of z(f)
// 256-VGPR tier (2 waves/SIMD), 1 block/CU. produces zpart[8][4096][256] f32
// ---------------------------------------------------------------------------
__global__ __launch_bounds__(512, 2) void vg_main(
    const float* __restrict__ x,      // [4096][256]
    const float* __restrict__ w1s,    // [256][64]
    const float* __restrict__ b1,     // [256][64]
    const __bf16* __restrict__ w2t,   // [256][16][64]
    const float* __restrict__ b2l,    // [256][8]
    const float* __restrict__ tau,    // [256][8]
    const __bf16* __restrict__ embt,  // [256][128][32]
    const __bf16* __restrict__ w1tf,  // [256][256][128]
    float* __restrict__ zpart)        // [8][4096][256]
{
  __shared__ __align__(16) __bf16 elds[2][128 * 128];  // 16B-XOR swizzled, 32KB each
  __shared__ __align__(16) float xs[128][33];
  __shared__ __align__(16) float ws1[2048], wb1[2048];
  __shared__ __align__(16) float wb2[256], wtau[256];

  const int g = blockIdx.x & 7;          // == XCD id (round-robin dispatch)
  const int r0 = (blockIdx.x >> 3) * 128;
  const int f0 = g * 32;
  const int t = threadIdx.x;
  const int w = t >> 6, l = t & 63, lo = l & 15, hi = l >> 4;
  const int wm = w >> 2, wn = w & 3;     // consume grid: 2M x 4N, 64x64/wave

  // ---- block init: x tile + per-f params into LDS
  for (int i = t; i < 4096; i += 512) {
    int rr = i >> 5, cc = i & 31;
    float v = x[(size_t)(r0 + rr) * 256 + f0 + cc];
    v = (v != v) ? 0.f : v;
    xs[rr][cc] = fminf(fmaxf(v, 0.f), 65536.f);
  }
  for (int i = t; i < 2048; i += 512) {
    ws1[i] = w1s[f0 * 64 + i];
    wb1[i] = b1[f0 * 64 + i];
  }
  if (t < 256) {
    wb2[t] = b2l[f0 * 8 + t];
    wtau[t] = tau[f0 * 8 + t];
  }
  __syncthreads();  // init visible before prologue produce (r3 lesson)

  // ---- producer: phases 1-3 for local f-index fi, writing elds[bsel]
  // wave w owns rows w*16 .. w*16+15
  auto produce = [&](int fi, int bsel) {
    const int f = f0 + fi;
    const int row = w * 16 + lo;

    // phase 1: h B-fragments (n=row, k = s*32+hi*8+j)
    const float xr = xs[row][fi];
    bf16x8 ha[2];
#pragma unroll
    for (int s = 0; s < 2; s++) {
      float4 wa = *(const float4*)(ws1 + fi * 64 + s * 32 + hi * 8);
      float4 wb = *(const float4*)(ws1 + fi * 64 + s * 32 + hi * 8 + 4);
      float4 ba = *(const float4*)(wb1 + fi * 64 + s * 32 + hi * 8);
      float4 bb = *(const float4*)(wb1 + fi * 64 + s * 32 + hi * 8 + 4);
      float hv[8];
      hv[0] = lrelu(xr * wa.x + ba.x);
      hv[1] = lrelu(xr * wa.y + ba.y);
      hv[2] = lrelu(xr * wa.z + ba.z);
      hv[3] = lrelu(xr * wa.w + ba.w);
      hv[4] = lrelu(xr * wb.x + bb.x);
      hv[5] = lrelu(xr * wb.y + bb.y);
      hv[6] = lrelu(xr * wb.z + bb.z);
      hv[7] = lrelu(xr * wb.w + bb.w);
#pragma unroll
      for (int j = 0; j < 8; j++) ha[s][j] = (__bf16)hv[j];
    }

    // phase 2 (swapped): g^T = MFMA(A=w2frag, B=ha)
    f32x4 gacc = {0.f, 0.f, 0.f, 0.f};
#pragma unroll
    for (int s = 0; s < 2; s++) {
      bf16x8 bw = *(const bf16x8*)&w2t[(f * 16 + lo) * 64 + s * 32 + hi * 8];
      gacc = MFMA16(bw, ha[s], gacc);
    }
    // softmax fully in-register: buckets hi*4+{0..3} local, partner via xor16
    const int bidx = fi * 8 + (hi & 1) * 4;
    float4 b2v = *(const float4*)&wb2[bidx];
    float4 tv = *(const float4*)&wtau[bidx];
    float gb[4];
#pragma unroll
    for (int r = 0; r < 4; r++) gb[r] = lrelu(gacc[r] + b2v[r]) * tv[r];
    float m01 = fmaxf(fmaxf(gb[0], gb[1]), fmaxf(gb[2], gb[3]));
    float mx = fmaxf(m01, __shfl_xor(m01, 16));
    float ev[4];
#pragma unroll
    for (int r = 0; r < 4; r++) ev[r] = __expf(gb[r] - mx);
    float s4 = (ev[0] + ev[1]) + (ev[2] + ev[3]);
    s4 += __shfl_xor(s4, 16);
    float inv = __builtin_amdgcn_rcpf(s4);
    float pv[4], ov[4];
#pragma unroll
    for (int r = 0; r < 4; r++) pv[r] = ev[r] * inv;
#pragma unroll
    for (int r = 0; r < 4; r++) ov[r] = __shfl_xor(pv[r], 16);
    const bool keep = (hi == 0);  // K-pad: only k=0..7 nonzero
    bf16x8 pa;
#pragma unroll
    for (int r = 0; r < 4; r++) {
      pa[r] = (__bf16)(keep ? pv[r] : 0.f);
      pa[4 + r] = (__bf16)(keep ? ov[r] : 0.f);
    }

    // phase 3 (swapped): e^T frags = MFMA(A=embt, B=pa) -> ds_write_b64
    const __bf16* ep = embt + (size_t)f * 4096;
    char* ebuf = (char*)&elds[bsel][0];
    const int swz = (row & 7) << 4;
    const int rbase = row * 256;
#pragma unroll
    for (int dblk = 0; dblk < 8; dblk++) {
      bf16x8 ebg = *(const bf16x8*)&ep[(dblk * 16 + lo) * 32 + hi * 8];
      f32x4 cz = {0.f, 0.f, 0.f, 0.f};
      f32x4 ef = MFMA16(ebg, pa, cz);
      bf16x4 pk;
#pragma unroll
      for (int r = 0; r < 4; r++) pk[r] = (__bf16)ef[r];
      *(bf16x4*)(ebuf + rbase + ((dblk * 32 + hi * 8) ^ swz)) = pk;
    }
  };

  // ---- prologue: all waves produce f-index 0 into buffer 0
  produce(0, 0);
  __syncthreads();

  f32x4 acc[4][4] = {};

  for (int i = 0; i < 32; i++) {
    const int cur = i & 1;

    // 1) issue B loads for THIS f early (L2 latency hidden by produce below)
    const __bf16* bp = w1tf + ((size_t)(f0 + i) * 256 + wn * 64) * 128;
    bf16x8 Bq[4][4];
#pragma unroll
    for (int ks = 0; ks < 4; ks++)
#pragma unroll
      for (int n = 0; n < 4; n++)
        Bq[ks][n] = *(const bf16x8*)&bp[(n * 16 + lo) * 128 + ks * 32 + hi * 8];

    // 2) produce e(f+1) into the other buffer (VALU/small-MFMA work)
    if (i < 31) produce(i + 1, cur ^ 1);

    // 3) consume e(f): z += e_tile @ W1T, wave = rows wm*64.. x cols wn*64..
    const char* abase = (const char*)&elds[cur][0];
#pragma unroll
    for (int ks = 0; ks < 4; ks++) {
      bf16x8 A[4];
#pragma unroll
      for (int m = 0; m < 4; m++) {
        int row = wm * 64 + m * 16 + lo;
        A[m] = *(const bf16x8*)(abase + row * 256 +
                                ((ks * 64 + hi * 16) ^ ((row & 7) << 4)));
      }
#pragma unroll
      for (int m = 0; m < 4; m++)
#pragma unroll
        for (int n = 0; n < 4; n++) acc[m][n] = MFMA16(A[m], Bq[ks][n], acc[m][n]);
    }
    __syncthreads();
  }

  float* zp = zpart + (size_t)g * (4096 * 256) + (size_t)r0 * 256;
#pragma unroll
  for (int m = 0; m < 4; m++)
#pragma unroll
    for (int n = 0; n < 4; n++)
#pragma unroll
      for (int r = 0; r < 4; r++) {
        int row = wm * 64 + m * 16 + hi * 4 + r;
        int col = wn * 64 + n * 16 + lo;
        zp[row * 256 + col] = acc[m][n][r];
      }
}

// ---------------------------------------------------------------------------
// z[b][n] = bf16(relu(sum_g zpart + b1p[n]))  (x4 vectorized)
// ---------------------------------------------------------------------------
__global__ void vg_zred(const float* __restrict__ zpart, const float* __restrict__ b1p,
                        __bf16* __restrict__ z) {
  int i4 = (blockIdx.x * 256 + threadIdx.x) * 4;  // 1048576 total
  float4 s = *(const float4*)&b1p[i4 & 255];
#pragma unroll
  for (int g = 0; g < 8; g++) {
    float4 v = *(const float4*)&zpart[(size_t)g * 1048576 + i4];
    s.x += v.x; s.y += v.y; s.z += v.z; s.w += v.w;
  }
  bf16x4 o;
  o[0] = (__bf16)fmaxf(s.x, 0.f);
  o[1] = (__bf16)fmaxf(s.y, 0.f);
  o[2] = (__bf16)fmaxf(s.z, 0.f);
  o[3] = (__bf16)fmaxf(s.w, 0.f);
  *(bf16x4*)&z[i4] = o;
}

// ---------------------------------------------------------------------------
// out = z @ W2 + b2   (M=4096, N=4096, K=256)
// ---------------------------------------------------------------------------
__global__ __launch_bounds__(256, 2) void vg_out(
    const __bf16* __restrict__ z,    // [4096][256]
    const __bf16* __restrict__ w2t,  // [4096][256]  (W2T[n][k])
    const float* __restrict__ b2,    // [4096]
    float* __restrict__ out)         // [4096][4096]
{
  const int m0 = (blockIdx.x & 31) * 128;
  const int n0 = (blockIdx.x >> 5) * 128;
  const int t = threadIdx.x, w = t >> 6, l = t & 63, lo = l & 15, hi = l >> 4;
  const int wm = w >> 1, wn = w & 1;  // 2x2 waves, 64x64 each
  f32x4 acc[4][4] = {};
#pragma unroll
  for (int ks = 0; ks < 8; ks++) {
    bf16x8 A[4], Bq[4];
#pragma unroll
    for (int m = 0; m < 4; m++)
      A[m] = *(const bf16x8*)&z[(size_t)(m0 + wm * 64 + m * 16 + lo) * 256 + ks * 32 + hi * 8];
#pragma unroll
    for (int n = 0; n < 4; n++)
      Bq[n] = *(const bf16x8*)&w2t[(size_t)(n0 + wn * 64 + n * 16 + lo) * 256 + ks * 32 + hi * 8];
#pragma unroll
    for (int m = 0; m < 4; m++)
#pragma unroll
      for (int n = 0; n < 4; n++) acc[m][n] = MFMA16(A[m], Bq[n], acc[m][n]);
  }
#pragma unroll
  for (int m = 0; m < 4; m++)
#pragma unroll
    for (int n = 0; n < 4; n++) {
      int col = n0 + wn * 64 + n * 16 + lo;
      float bv = b2[col];
#pragma unroll
      for (int r = 0; r < 4; r++) {
        int row = m0 + wm * 64 + m * 16 + hi * 4 + r;
        out[(size_t)row * 4096 + col] = acc[m][n][r] + bv;
      }
    }
}

// ---------------------------------------------------------------------------
extern "C" void kernel_launch(void* const* d_in, const int* in_sizes, int n_in,
                              void* d_out, int out_size, void* d_ws, size_t ws_size,
                              hipStream_t stream) {
  const float* x   = (const float*)d_in[0];
  const float* lw1 = (const float*)d_in[1];
  const float* b1  = (const float*)d_in[2];
  const float* lw2 = (const float*)d_in[3];
  const float* b2l = (const float*)d_in[4];
  const float* tau = (const float*)d_in[5];
  const float* emb = (const float*)d_in[6];
  const float* pw1 = (const float*)d_in[7];
  const float* pb1 = (const float*)d_in[8];
  const float* pw2 = (const float*)d_in[9];
  const float* pb2 = (const float*)d_in[10];
  float* out = (float*)d_out;

  char* ws = (char*)d_ws;
  float*  w1s  = (float*)(ws + 0);          //      65536 B
  __bf16* w2t  = (__bf16*)(ws + 65536);     //     524288 B
  __bf16* embt = (__bf16*)(ws + 589824);    //    2097152 B
  __bf16* w1tf = (__bf16*)(ws + 2686976);   //   16777216 B
  __bf16* w2t3 = (__bf16*)(ws + 19464192);  //    2097152 B
  __bf16* z    = (__bf16*)(ws + 21561344);  //    2097152 B
  float*  zpart = (float*)(ws + 23658496);  //   33554432 B  (total 57212928)

  vg_w1s<<<64, 256, 0, stream>>>(lw1, w1s);
  vg_w2t<<<1024, 256, 0, stream>>>(lw2, w2t);
  vg_embt<<<4096, 256, 0, stream>>>(emb, embt);
  vg_w1tf<<<256, 256, 0, stream>>>(pw1, w1tf);
  vg_transpose<<<256, 256, 0, stream>>>(pw2, w2t3, 256, 4096);
  vg_main<<<256, 512, 0, stream>>>(x, w1s, b1, w2t, b2l, tau, embt, w1tf, zpart);
  vg_zred<<<1024, 256, 0, stream>>>(zpart, pb1, z);
  vg_out<<<1024, 256, 0, stream>>>(z, w2t3, pb2, out);
}

// Round 7
// 238.177 us; speedup vs baseline: 1.1624x; 1.0263x over previous
//
#include <hip/hip_runtime.h>
#include <hip/hip_bf16.h>

typedef __bf16 bf16x8 __attribute__((ext_vector_type(8)));
typedef __bf16 bf16x4 __attribute__((ext_vector_type(4)));
typedef float  f32x4  __attribute__((ext_vector_type(4)));

#define MFMA16(a, b, c) __builtin_amdgcn_mfma_f32_16x16x32_bf16(a, b, c, 0, 0, 0)

__device__ __forceinline__ float lrelu(float v) { return fmaxf(v, 0.01f * v); }

// ---------------------------------------------------------------------------
// prep kernels
// ---------------------------------------------------------------------------

// w1s[f][h] = sum_i linear1_w[f][i][h]   (16384 elements)
__global__ void vg_w1s(const float* __restrict__ lw1, float* __restrict__ w1s) {
  int i = blockIdx.x * 256 + threadIdx.x;
  int f = i >> 6, h = i & 63;
  w1s[i] = lw1[f * 192 + h] + lw1[f * 192 + 64 + h] + lw1[f * 192 + 128 + h];
}

// W2T[f][n(16,pad)][k(64)] = bf16(linear2_w[f][k][n]) , n>=8 -> 0   (262144)
__global__ void vg_w2t(const float* __restrict__ lw2, __bf16* __restrict__ w2t) {
  int i = blockIdx.x * 256 + threadIdx.x;
  int f = i >> 10, n = (i >> 6) & 15, k = i & 63;
  float v = (n < 8) ? lw2[(f * 64 + k) * 8 + n] : 0.f;
  w2t[i] = (__bf16)v;
}

// embT[f][d(128)][k(32,pad)] = bf16(emb[f][k][d]) , k>=8 -> 0   (1048576)
__global__ void vg_embt(const float* __restrict__ emb, __bf16* __restrict__ embt) {
  int i = blockIdx.x * 256 + threadIdx.x;
  int f = i >> 12, d = (i >> 5) & 127, k = i & 31;
  float v = (k < 8) ? emb[(f * 8 + k) * 128 + d] : 0.f;
  embt[i] = (__bf16)v;
}

// w1tf[f][n(256)][k(128)] = bf16(pw1[(f*128+k)*256 + n])  -- per-f contiguous
__global__ void vg_w1tf(const float* __restrict__ pw1, __bf16* __restrict__ w1tf) {
  __shared__ __bf16 tl[128][258];
  const int f = blockIdx.x, t = threadIdx.x;
  const float* src = pw1 + (size_t)f * 32768;
  for (int idx = t; idx < 32768; idx += 256) {
    int k = idx >> 8, n = idx & 255;
    tl[k][n] = (__bf16)src[idx];
  }
  __syncthreads();
  __bf16* dst = w1tf + (size_t)f * 32768;
  for (int idx = t; idx < 32768; idx += 256) {
    int n = idx >> 7, k = idx & 127;
    dst[idx] = tl[k][n];
  }
}

// transpose [R][C] f32 -> [C][R] bf16, 64x64 LDS tiles (for proj_w2)
__global__ void vg_transpose(const float* __restrict__ in, __bf16* __restrict__ outT,
                             int R, int C) {
  __shared__ float tile[64][65];
  int tilesPerRow = C >> 6;
  int tr = blockIdx.x / tilesPerRow, tc = blockIdx.x % tilesPerRow;
  int r0 = tr * 64, c0 = tc * 64;
  int t = threadIdx.x;
  int cc = t & 63, rq = t >> 6;
#pragma unroll 4
  for (int i = 0; i < 16; i++) {
    int rr = rq * 16 + i;
    tile[rr][cc] = in[(size_t)(r0 + rr) * C + c0 + cc];
  }
  __syncthreads();
  int rr2 = t & 63, cq = t >> 6;
#pragma unroll 4
  for (int i = 0; i < 16; i++) {
    int cc2 = cq * 16 + i;
    outT[(size_t)(c0 + cc2) * R + r0 + rr2] = (__bf16)tile[rr2][cc2];
  }
}

// ---------------------------------------------------------------------------
// main fused kernel: per block = 64 rows x one f-group (32 f's)
// role split at 256-VGPR tier: waves 0-3 consumers (64x64 acc each),
// waves 4-7 producers (16 rows each, next-f globals prefetched in regs)
// ---------------------------------------------------------------------------
__global__ __launch_bounds__(512, 2) void vg_main(
    const float* __restrict__ x,      // [4096][256]
    const float* __restrict__ w1s,    // [256][64]
    const float* __restrict__ b1,     // [256][64]
    const __bf16* __restrict__ w2t,   // [256][16][64]
    const float* __restrict__ b2l,    // [256][8]
    const float* __restrict__ tau,    // [256][8]
    const __bf16* __restrict__ embt,  // [256][128][32]
    const __bf16* __restrict__ w1tf,  // [256][256][128]
    float* __restrict__ zpart)        // [8][4096][256]
{
  __shared__ __align__(16) __bf16 elds[2][64 * 128];  // 16B-XOR swizzled
  __shared__ __align__(16) float xs[64][33];
  __shared__ __align__(16) float ws1[2048], wb1[2048];
  __shared__ __align__(16) float wb2[256], wtau[256];

  const int g = blockIdx.x & 7;          // == XCD id (round-robin dispatch)
  const int r0 = (blockIdx.x >> 3) * 64;
  const int f0 = g * 32;
  const int t = threadIdx.x;
  const int w = t >> 6, l = t & 63, lo = l & 15, hi = l >> 4;
  const bool producer = (w >= 4);
  const int pw = w & 3;                  // producer row-group / consumer col-group

  // ---- block init: x tile + per-f params into LDS
  for (int i = t; i < 2048; i += 512) {
    int rr = i >> 5, cc = i & 31;
    float v = x[(size_t)(r0 + rr) * 256 + f0 + cc];
    v = (v != v) ? 0.f : v;
    xs[rr][cc] = fminf(fmaxf(v, 0.f), 65536.f);
  }
  for (int i = t; i < 2048; i += 512) {
    ws1[i] = w1s[f0 * 64 + i];
    wb1[i] = b1[f0 * 64 + i];
  }
  if (t < 256) {
    wb2[t] = b2l[f0 * 8 + t];
    wtau[t] = tau[f0 * 8 + t];
  }
  __syncthreads();  // init visible before prologue produce (r3 lesson)

  // ================= producer state: next-f operands in registers ==========
  bf16x8 w2r[2], ebr[8];  // 40 VGPR prefetch window

  auto load_pf = [&](int fi) {  // issue global loads for f0+fi into regs
    const int f = f0 + fi;
#pragma unroll
    for (int s = 0; s < 2; s++)
      w2r[s] = *(const bf16x8*)&w2t[(f * 16 + lo) * 64 + s * 32 + hi * 8];
    const __bf16* ep = embt + (size_t)f * 4096;
#pragma unroll
    for (int d = 0; d < 8; d++)
      ebr[d] = *(const bf16x8*)&ep[(d * 16 + lo) * 32 + hi * 8];
  };

  // compute e(f0+fi) from prefetched regs, write elds[bsel]
  auto produce = [&](int fi, int bsel) {
    const int row = pw * 16 + lo;

    // phase 1: h B-fragments (n=row, k = s*32+hi*8+j)
    const float xr = xs[row][fi];
    bf16x8 ha[2];
#pragma unroll
    for (int s = 0; s < 2; s++) {
      float4 wa = *(const float4*)(ws1 + fi * 64 + s * 32 + hi * 8);
      float4 wb = *(const float4*)(ws1 + fi * 64 + s * 32 + hi * 8 + 4);
      float4 ba = *(const float4*)(wb1 + fi * 64 + s * 32 + hi * 8);
      float4 bb = *(const float4*)(wb1 + fi * 64 + s * 32 + hi * 8 + 4);
      float hv[8];
      hv[0] = lrelu(xr * wa.x + ba.x);
      hv[1] = lrelu(xr * wa.y + ba.y);
      hv[2] = lrelu(xr * wa.z + ba.z);
      hv[3] = lrelu(xr * wa.w + ba.w);
      hv[4] = lrelu(xr * wb.x + bb.x);
      hv[5] = lrelu(xr * wb.y + bb.y);
      hv[6] = lrelu(xr * wb.z + bb.z);
      hv[7] = lrelu(xr * wb.w + bb.w);
#pragma unroll
      for (int j = 0; j < 8; j++) ha[s][j] = (__bf16)hv[j];
    }

    // phase 2 (swapped): g^T = MFMA(A=w2r, B=ha)
    f32x4 gacc = {0.f, 0.f, 0.f, 0.f};
#pragma unroll
    for (int s = 0; s < 2; s++) gacc = MFMA16(w2r[s], ha[s], gacc);

    // softmax in-register: buckets hi*4+{0..3} local, partner via xor16
    const int bidx = fi * 8 + (hi & 1) * 4;
    float4 b2v = *(const float4*)&wb2[bidx];
    float4 tv = *(const float4*)&wtau[bidx];
    float gb[4];
#pragma unroll
    for (int r = 0; r < 4; r++) gb[r] = lrelu(gacc[r] + b2v[r]) * tv[r];
    float m01 = fmaxf(fmaxf(gb[0], gb[1]), fmaxf(gb[2], gb[3]));
    float mx = fmaxf(m01, __shfl_xor(m01, 16));
    float ev[4];
#pragma unroll
    for (int r = 0; r < 4; r++) ev[r] = __expf(gb[r] - mx);
    float s4 = (ev[0] + ev[1]) + (ev[2] + ev[3]);
    s4 += __shfl_xor(s4, 16);
    float inv = __builtin_amdgcn_rcpf(s4);
    float pv[4], ov[4];
#pragma unroll
    for (int r = 0; r < 4; r++) pv[r] = ev[r] * inv;
#pragma unroll
    for (int r = 0; r < 4; r++) ov[r] = __shfl_xor(pv[r], 16);
    const bool keep = (hi == 0);  // K-pad: only k=0..7 nonzero
    bf16x8 pa;
#pragma unroll
    for (int r = 0; r < 4; r++) {
      pa[r] = (__bf16)(keep ? pv[r] : 0.f);
      pa[4 + r] = (__bf16)(keep ? ov[r] : 0.f);
    }

    // phase 3 (swapped): e^T frags = MFMA(A=ebr, B=pa) -> ds_write_b64
    char* ebuf = (char*)&elds[bsel][0];
    const int swz = (row & 7) << 4;
    const int rbase = row * 256;
#pragma unroll
    for (int dblk = 0; dblk < 8; dblk++) {
      f32x4 cz = {0.f, 0.f, 0.f, 0.f};
      f32x4 ef = MFMA16(ebr[dblk], pa, cz);
      bf16x4 pk;
#pragma unroll
      for (int r = 0; r < 4; r++) pk[r] = (__bf16)ef[r];
      *(bf16x4*)(ebuf + rbase + ((dblk * 32 + hi * 8) ^ swz)) = pk;
    }
  };

  // ---- prologue: producers make f-index 0 into buffer 0, prefetch f=1
  if (producer) {
    load_pf(0);
    produce(0, 0);
    load_pf(1);
  }
  __syncthreads();

  f32x4 acc[4][4] = {};

  for (int i = 0; i < 32; i++) {
    const int cur = i & 1;
    if (producer) {
      if (i < 31) {
        produce(i + 1, cur ^ 1);      // uses regs prefetched last iter
        if (i < 30) load_pf(i + 2);   // overwrite window after last use
      }
    } else {
      // ---- consumer: z += e_tile(f0+i) @ W1T, wave = 64 rows x 64 cols
      const __bf16* bp = w1tf + ((size_t)(f0 + i) * 256 + pw * 64) * 128;
      bf16x8 Bq[4][4];  // all 16 B loads issued up front (L2-latency hidden)
#pragma unroll
      for (int ks = 0; ks < 4; ks++)
#pragma unroll
        for (int n = 0; n < 4; n++)
          Bq[ks][n] = *(const bf16x8*)&bp[(n * 16 + lo) * 128 + ks * 32 + hi * 8];

      const char* abase = (const char*)&elds[cur][0];
      __builtin_amdgcn_s_setprio(1);
#pragma unroll
      for (int ks = 0; ks < 4; ks++) {
        bf16x8 A[4];
#pragma unroll
        for (int m = 0; m < 4; m++) {
          int row = m * 16 + lo;
          A[m] = *(const bf16x8*)(abase + row * 256 +
                                  ((ks * 64 + hi * 16) ^ ((row & 7) << 4)));
        }
#pragma unroll
        for (int m = 0; m < 4; m++)
#pragma unroll
          for (int n = 0; n < 4; n++) acc[m][n] = MFMA16(A[m], Bq[ks][n], acc[m][n]);
      }
      __builtin_amdgcn_s_setprio(0);
    }
    __syncthreads();
  }

  if (!producer) {
    float* zp = zpart + (size_t)g * (4096 * 256) + (size_t)r0 * 256;
#pragma unroll
    for (int m = 0; m < 4; m++)
#pragma unroll
      for (int n = 0; n < 4; n++)
#pragma unroll
        for (int r = 0; r < 4; r++) {
          int row = m * 16 + hi * 4 + r;
          int col = pw * 64 + n * 16 + lo;
          zp[row * 256 + col] = acc[m][n][r];
        }
  }
}

// ---------------------------------------------------------------------------
// z[b][n] = bf16(relu(sum_g zpart + b1p[n]))  (x4 vectorized)
// ---------------------------------------------------------------------------
__global__ void vg_zred(const float* __restrict__ zpart, const float* __restrict__ b1p,
                        __bf16* __restrict__ z) {
  int i4 = (blockIdx.x * 256 + threadIdx.x) * 4;  // 1048576 total
  float4 s = *(const float4*)&b1p[i4 & 255];
#pragma unroll
  for (int g = 0; g < 8; g++) {
    float4 v = *(const float4*)&zpart[(size_t)g * 1048576 + i4];
    s.x += v.x; s.y += v.y; s.z += v.z; s.w += v.w;
  }
  bf16x4 o;
  o[0] = (__bf16)fmaxf(s.x, 0.f);
  o[1] = (__bf16)fmaxf(s.y, 0.f);
  o[2] = (__bf16)fmaxf(s.z, 0.f);
  o[3] = (__bf16)fmaxf(s.w, 0.f);
  *(bf16x4*)&z[i4] = o;
}

// ---------------------------------------------------------------------------
// out = z @ W2 + b2   (M=4096, N=4096, K=256)
// ---------------------------------------------------------------------------
__global__ __launch_bounds__(256, 2) void vg_out(
    const __bf16* __restrict__ z,    // [4096][256]
    const __bf16* __restrict__ w2t,  // [4096][256]  (W2T[n][k])
    const float* __restrict__ b2,    // [4096]
    float* __restrict__ out)         // [4096][4096]
{
  const int m0 = (blockIdx.x & 31) * 128;
  const int n0 = (blockIdx.x >> 5) * 128;
  const int t = threadIdx.x, w = t >> 6, l = t & 63, lo = l & 15, hi = l >> 4;
  const int wm = w >> 1, wn = w & 1;  // 2x2 waves, 64x64 each
  f32x4 acc[4][4] = {};
#pragma unroll
  for (int ks = 0; ks < 8; ks++) {
    bf16x8 A[4], Bq[4];
#pragma unroll
    for (int m = 0; m < 4; m++)
      A[m] = *(const bf16x8*)&z[(size_t)(m0 + wm * 64 + m * 16 + lo) * 256 + ks * 32 + hi * 8];
#pragma unroll
    for (int n = 0; n < 4; n++)
      Bq[n] = *(const bf16x8*)&w2t[(size_t)(n0 + wn * 64 + n * 16 + lo) * 256 + ks * 32 + hi * 8];
#pragma unroll
    for (int m = 0; m < 4; m++)
#pragma unroll
      for (int n = 0; n < 4; n++) acc[m][n] = MFMA16(A[m], Bq[n], acc[m][n]);
  }
#pragma unroll
  for (int m = 0; m < 4; m++)
#pragma unroll
    for (int n = 0; n < 4; n++) {
      int col = n0 + wn * 64 + n * 16 + lo;
      float bv = b2[col];
#pragma unroll
      for (int r = 0; r < 4; r++) {
        int row = m0 + wm * 64 + m * 16 + hi * 4 + r;
        out[(size_t)row * 4096 + col] = acc[m][n][r] + bv;
      }
    }
}

// ---------------------------------------------------------------------------
extern "C" void kernel_launch(void* const* d_in, const int* in_sizes, int n_in,
                              void* d_out, int out_size, void* d_ws, size_t ws_size,
                              hipStream_t stream) {
  const float* x   = (const float*)d_in[0];
  const float* lw1 = (const float*)d_in[1];
  const float* b1  = (const float*)d_in[2];
  const float* lw2 = (const float*)d_in[3];
  const float* b2l = (const float*)d_in[4];
  const float* tau = (const float*)d_in[5];
  const float* emb = (const float*)d_in[6];
  const float* pw1 = (const float*)d_in[7];
  const float* pb1 = (const float*)d_in[8];
  const float* pw2 = (const float*)d_in[9];
  const float* pb2 = (const float*)d_in[10];
  float* out = (float*)d_out;

  char* ws = (char*)d_ws;
  float*  w1s  = (float*)(ws + 0);          //      65536 B
  __bf16* w2t  = (__bf16*)(ws + 65536);     //     524288 B
  __bf16* embt = (__bf16*)(ws + 589824);    //    2097152 B
  __bf16* w1tf = (__bf16*)(ws + 2686976);   //   16777216 B
  __bf16* w2t3 = (__bf16*)(ws + 19464192);  //    2097152 B
  __bf16* z    = (__bf16*)(ws + 21561344);  //    2097152 B
  float*  zpart = (float*)(ws + 23658496);  //   33554432 B  (total 57212928)

  vg_w1s<<<64, 256, 0, stream>>>(lw1, w1s);
  vg_w2t<<<1024, 256, 0, stream>>>(lw2, w2t);
  vg_embt<<<4096, 256, 0, stream>>>(emb, embt);
  vg_w1tf<<<256, 256, 0, stream>>>(pw1, w1tf);
  vg_transpose<<<256, 256, 0, stream>>>(pw2, w2t3, 256, 4096);
  vg_main<<<512, 512, 0, stream>>>(x, w1s, b1, w2t, b2l, tau, embt, w1tf, zpart);
  vg_zred<<<1024, 256, 0, stream>>>(zpart, pb1, z);
  vg_out<<<1024, 256, 0, stream>>>(z, w2t3, pb2, out);
}

// Round 8
// 125.950 us; speedup vs baseline: 2.1982x; 1.8910x over previous
//
#include <hip/hip_runtime.h>
#include <hip/hip_bf16.h>

typedef __bf16 bf16x8 __attribute__((ext_vector_type(8)));
typedef __bf16 bf16x4 __attribute__((ext_vector_type(4)));
typedef float  f32x4  __attribute__((ext_vector_type(4)));

#define MFMA16(a, b, c) __builtin_amdgcn_mfma_f32_16x16x32_bf16(a, b, c, 0, 0, 0)

__device__ __forceinline__ float lrelu(float v) { return fmaxf(v, 0.01f * v); }

// ---------------------------------------------------------------------------
// prep kernels
// ---------------------------------------------------------------------------

// w1s[f][h] = sum_i linear1_w[f][i][h]   (16384 elements)
__global__ void vg_w1s(const float* __restrict__ lw1, float* __restrict__ w1s) {
  int i = blockIdx.x * 256 + threadIdx.x;
  int f = i >> 6, h = i & 63;
  w1s[i] = lw1[f * 192 + h] + lw1[f * 192 + 64 + h] + lw1[f * 192 + 128 + h];
}

// W2T[f][n(16)][k(64)] = bf16(linear2_w[f][k][n&7])  -- rows 8..15 REPLICATE
// rows 0..7 so every hi-lane group computes true buckets (round-8 fix)
__global__ void vg_w2t(const float* __restrict__ lw2, __bf16* __restrict__ w2t) {
  int i = blockIdx.x * 256 + threadIdx.x;
  int f = i >> 10, n = (i >> 6) & 15, k = i & 63;
  w2t[i] = (__bf16)lw2[(f * 64 + k) * 8 + (n & 7)];
}

// weffT[n(256)][f*8+k] = bf16( sum_d emb[f][k][d] * pw1[(f*128+d)*256 + n] )
// (the key algebraic collapse: W_eff = emb @ W1, K shrinks 32768 -> 2048)
__global__ void vg_weff(const float* __restrict__ emb, const float* __restrict__ pw1,
                        __bf16* __restrict__ weffT) {
  __shared__ float es[8][128];
  const int f = blockIdx.x, n = threadIdx.x;
  for (int i = n; i < 1024; i += 256) es[i >> 7][i & 127] = emb[f * 1024 + i];
  __syncthreads();
  float s[8] = {0.f, 0.f, 0.f, 0.f, 0.f, 0.f, 0.f, 0.f};
  const float* pp = pw1 + (size_t)f * 128 * 256 + n;
#pragma unroll 4
  for (int d = 0; d < 128; d++) {
    float wv = pp[(size_t)d * 256];
#pragma unroll
    for (int k = 0; k < 8; k++) s[k] += es[k][d] * wv;
  }
  bf16x8 o;
#pragma unroll
  for (int k = 0; k < 8; k++) o[k] = (__bf16)s[k];
  *(bf16x8*)&weffT[(size_t)n * 2048 + f * 8] = o;
}

// transpose [R][C] f32 -> [C][R] bf16, 64x64 LDS tiles (for proj_w2)
__global__ void vg_transpose(const float* __restrict__ in, __bf16* __restrict__ outT,
                             int R, int C) {
  __shared__ float tile[64][65];
  int tilesPerRow = C >> 6;
  int tr = blockIdx.x / tilesPerRow, tc = blockIdx.x % tilesPerRow;
  int r0 = tr * 64, c0 = tc * 64;
  int t = threadIdx.x;
  int cc = t & 63, rq = t >> 6;
#pragma unroll 4
  for (int i = 0; i < 16; i++) {
    int rr = rq * 16 + i;
    tile[rr][cc] = in[(size_t)(r0 + rr) * C + c0 + cc];
  }
  __syncthreads();
  int rr2 = t & 63, cq = t >> 6;
#pragma unroll 4
  for (int i = 0; i < 16; i++) {
    int cc2 = cq * 16 + i;
    outT[(size_t)(c0 + cc2) * R + r0 + rr2] = (__bf16)tile[rr2][cc2];
  }
}

// ---------------------------------------------------------------------------
// main fused kernel: grid = 64 row-tiles x 8 f-groups, 256 thr (4 waves).
// Each wave independently owns 16 rows: builds p (phases 1-2 + softmax) for
// 4 f's at a time (lane hi keeps f=fbase+hi's 8 buckets -> dense K=32 A-frag)
// and accumulates z[16x256] against L2-resident W_effT. No barriers in loop.
// ---------------------------------------------------------------------------
__global__ __launch_bounds__(256, 2) void vg_main(
    const float* __restrict__ x,      // [4096][256]
    const float* __restrict__ w1s,    // [256][64]
    const float* __restrict__ b1,     // [256][64]
    const __bf16* __restrict__ w2t,   // [256][16][64] (rows 8-15 replicas)
    const float* __restrict__ b2l,    // [256][8]
    const float* __restrict__ tau,    // [256][8]
    const __bf16* __restrict__ weffT, // [256 n][2048 k]  k = f*8+bucket
    float* __restrict__ zpart)        // [8][4096][256]
{
  __shared__ __align__(16) float xs[64][33];
  __shared__ __align__(16) float ws1[2048], wb1[2048];
  __shared__ __align__(16) float wb2[256], wtau[256];

  const int g = blockIdx.x & 7;          // f-group == XCD pin
  const int r0 = (blockIdx.x >> 3) * 64;
  const int f0 = g * 32;
  const int t = threadIdx.x;
  const int w = t >> 6, l = t & 63, lo = l & 15, hi = l >> 4;

  // ---- init: x tile [64][32] + per-f params into LDS
  for (int i = t; i < 2048; i += 256) {
    int rr = i >> 5, cc = i & 31;
    float v = x[(size_t)(r0 + rr) * 256 + f0 + cc];
    v = (v != v) ? 0.f : v;
    xs[rr][cc] = fminf(fmaxf(v, 0.f), 65536.f);
    ws1[i] = w1s[f0 * 64 + i];
    wb1[i] = b1[f0 * 64 + i];
  }
  wb2[t] = b2l[f0 * 8 + t];
  wtau[t] = tau[f0 * 8 + t];
  __syncthreads();  // init visible (r3 lesson); ONLY barrier in the kernel

  const int row = w * 16 + lo;  // wave's rows: r0 + w*16 + (0..15)

  f32x4 acc[16] = {};

  for (int fq = 0; fq < 8; fq++) {
    bf16x8 paq = {};
#pragma unroll
    for (int sub = 0; sub < 4; sub++) {
      const int fi = fq * 4 + sub;
      const int f = f0 + fi;

      // phase 1: h B-fragments (k = s*32+hi*8+j, col=row)
      const float xr = xs[row][fi];
      bf16x8 ha[2];
#pragma unroll
      for (int s = 0; s < 2; s++) {
        float4 wa = *(const float4*)(ws1 + fi * 64 + s * 32 + hi * 8);
        float4 wb = *(const float4*)(ws1 + fi * 64 + s * 32 + hi * 8 + 4);
        float4 ba = *(const float4*)(wb1 + fi * 64 + s * 32 + hi * 8);
        float4 bb = *(const float4*)(wb1 + fi * 64 + s * 32 + hi * 8 + 4);
        float hv[8];
        hv[0] = lrelu(xr * wa.x + ba.x);
        hv[1] = lrelu(xr * wa.y + ba.y);
        hv[2] = lrelu(xr * wa.z + ba.z);
        hv[3] = lrelu(xr * wa.w + ba.w);
        hv[4] = lrelu(xr * wb.x + bb.x);
        hv[5] = lrelu(xr * wb.y + bb.y);
        hv[6] = lrelu(xr * wb.z + bb.z);
        hv[7] = lrelu(xr * wb.w + bb.w);
#pragma unroll
        for (int j = 0; j < 8; j++) ha[s][j] = (__bf16)hv[j];
      }

      // phase 2 (swapped): g^T = MFMA(A=w2frag, B=ha)
      // lane (lo,hi): col=lo=row-idx, rows hi*4+r = bucket (mod-8 replicated)
      f32x4 gacc = {0.f, 0.f, 0.f, 0.f};
#pragma unroll
      for (int s = 0; s < 2; s++) {
        bf16x8 bw = *(const bf16x8*)&w2t[(f * 16 + lo) * 64 + s * 32 + hi * 8];
        gacc = MFMA16(bw, ha[s], gacc);
      }

      // softmax in-register: this lane holds buckets (hi&1)*4..+3; partner xor16
      const int bidx = fi * 8 + (hi & 1) * 4;
      float4 b2v = *(const float4*)&wb2[bidx];
      float4 tv = *(const float4*)&wtau[bidx];
      float gb[4];
#pragma unroll
      for (int r = 0; r < 4; r++) gb[r] = lrelu(gacc[r] + b2v[r]) * tv[r];
      float m01 = fmaxf(fmaxf(gb[0], gb[1]), fmaxf(gb[2], gb[3]));
      float mx = fmaxf(m01, __shfl_xor(m01, 16));
      float ev[4];
#pragma unroll
      for (int r = 0; r < 4; r++) ev[r] = __expf(gb[r] - mx);
      float s4 = (ev[0] + ev[1]) + (ev[2] + ev[3]);
      s4 += __shfl_xor(s4, 16);
      float inv = __builtin_amdgcn_rcpf(s4);
      float pv[4], ov[4];
#pragma unroll
      for (int r = 0; r < 4; r++) pv[r] = ev[r] * inv;
#pragma unroll
      for (int r = 0; r < 4; r++) ov[r] = __shfl_xor(pv[r], 16);

      // full 8 buckets in order 0..7 (parity decides which half is local)
      bf16x8 full8;
#pragma unroll
      for (int r = 0; r < 4; r++) {
        full8[r]     = (__bf16)((hi & 1) ? ov[r] : pv[r]);
        full8[4 + r] = (__bf16)((hi & 1) ? pv[r] : ov[r]);
      }
      if (hi == sub) paq = full8;  // lane hi keeps f = fbase+hi
    }

    // z-GEMM step: acc += paq[16 rows x K32] @ W_effT quad [K32 x 256]
    const __bf16* bp = weffT + (size_t)(f0 + fq * 4) * 8 + hi * 8;
#pragma unroll
    for (int n = 0; n < 16; n++) {
      bf16x8 Bq = *(const bf16x8*)&bp[(size_t)(n * 16 + lo) * 2048];
      acc[n] = MFMA16(paq, Bq, acc[n]);
    }
  }

  // write zpart: wave's 16 rows x 256 cols
  float* zp = zpart + (size_t)g * (4096 * 256) + (size_t)(r0 + w * 16) * 256;
#pragma unroll
  for (int n = 0; n < 16; n++)
#pragma unroll
    for (int r = 0; r < 4; r++)
      zp[(hi * 4 + r) * 256 + n * 16 + lo] = acc[n][r];
}

// ---------------------------------------------------------------------------
// z[b][n] = bf16(relu(sum_g zpart + b1p[n]))  (x4 vectorized)
// ---------------------------------------------------------------------------
__global__ void vg_zred(const float* __restrict__ zpart, const float* __restrict__ b1p,
                        __bf16* __restrict__ z) {
  int i4 = (blockIdx.x * 256 + threadIdx.x) * 4;  // 1048576 total
  float4 s = *(const float4*)&b1p[i4 & 255];
#pragma unroll
  for (int g = 0; g < 8; g++) {
    float4 v = *(const float4*)&zpart[(size_t)g * 1048576 + i4];
    s.x += v.x; s.y += v.y; s.z += v.z; s.w += v.w;
  }
  bf16x4 o;
  o[0] = (__bf16)fmaxf(s.x, 0.f);
  o[1] = (__bf16)fmaxf(s.y, 0.f);
  o[2] = (__bf16)fmaxf(s.z, 0.f);
  o[3] = (__bf16)fmaxf(s.w, 0.f);
  *(bf16x4*)&z[i4] = o;
}

// ---------------------------------------------------------------------------
// out = z @ W2 + b2   (M=4096, N=4096, K=256)
// ---------------------------------------------------------------------------
__global__ __launch_bounds__(256, 2) void vg_out(
    const __bf16* __restrict__ z,    // [4096][256]
    const __bf16* __restrict__ w2t,  // [4096][256]  (W2T[n][k])
    const float* __restrict__ b2,    // [4096]
    float* __restrict__ out)         // [4096][4096]
{
  const int m0 = (blockIdx.x & 31) * 128;
  const int n0 = (blockIdx.x >> 5) * 128;
  const int t = threadIdx.x, w = t >> 6, l = t & 63, lo = l & 15, hi = l >> 4;
  const int wm = w >> 1, wn = w & 1;  // 2x2 waves, 64x64 each
  f32x4 acc[4][4] = {};
#pragma unroll
  for (int ks = 0; ks < 8; ks++) {
    bf16x8 A[4], Bq[4];
#pragma unroll
    for (int m = 0; m < 4; m++)
      A[m] = *(const bf16x8*)&z[(size_t)(m0 + wm * 64 + m * 16 + lo) * 256 + ks * 32 + hi * 8];
#pragma unroll
    for (int n = 0; n < 4; n++)
      Bq[n] = *(const bf16x8*)&w2t[(size_t)(n0 + wn * 64 + n * 16 + lo) * 256 + ks * 32 + hi * 8];
#pragma unroll
    for (int m = 0; m < 4; m++)
#pragma unroll
      for (int n = 0; n < 4; n++) acc[m][n] = MFMA16(A[m], Bq[n], acc[m][n]);
  }
#pragma unroll
  for (int m = 0; m < 4; m++)
#pragma unroll
    for (int n = 0; n < 4; n++) {
      int col = n0 + wn * 64 + n * 16 + lo;
      float bv = b2[col];
#pragma unroll
      for (int r = 0; r < 4; r++) {
        int row = m0 + wm * 64 + m * 16 + hi * 4 + r;
        out[(size_t)row * 4096 + col] = acc[m][n][r] + bv;
      }
    }
}

// ---------------------------------------------------------------------------
extern "C" void kernel_launch(void* const* d_in, const int* in_sizes, int n_in,
                              void* d_out, int out_size, void* d_ws, size_t ws_size,
                              hipStream_t stream) {
  const float* x   = (const float*)d_in[0];
  const float* lw1 = (const float*)d_in[1];
  const float* b1  = (const float*)d_in[2];
  const float* lw2 = (const float*)d_in[3];
  const float* b2l = (const float*)d_in[4];
  const float* tau = (const float*)d_in[5];
  const float* emb = (const float*)d_in[6];
  const float* pw1 = (const float*)d_in[7];
  const float* pb1 = (const float*)d_in[8];
  const float* pw2 = (const float*)d_in[9];
  const float* pb2 = (const float*)d_in[10];
  float* out = (float*)d_out;

  char* ws = (char*)d_ws;
  float*  w1s   = (float*)(ws + 0);         //   65536 B
  __bf16* w2t   = (__bf16*)(ws + 65536);    //  524288 B
  __bf16* weffT = (__bf16*)(ws + 589824);   // 1048576 B
  __bf16* w2t3  = (__bf16*)(ws + 1638400);  // 2097152 B
  __bf16* z     = (__bf16*)(ws + 3735552);  // 2097152 B
  float*  zpart = (float*)(ws + 5832704);   // 33554432 B (end ~39.4 MB)

  vg_w1s<<<64, 256, 0, stream>>>(lw1, w1s);
  vg_w2t<<<1024, 256, 0, stream>>>(lw2, w2t);
  vg_weff<<<256, 256, 0, stream>>>(emb, pw1, weffT);
  vg_transpose<<<256, 256, 0, stream>>>(pw2, w2t3, 256, 4096);
  vg_main<<<512, 256, 0, stream>>>(x, w1s, b1, w2t, b2l, tau, weffT, zpart);
  vg_zred<<<1024, 256, 0, stream>>>(zpart, pb1, z);
  vg_out<<<1024, 256, 0, stream>>>(z, w2t3, pb2, out);
}

// Round 9
// 121.815 us; speedup vs baseline: 2.2729x; 1.0339x over previous
//
#include <hip/hip_runtime.h>
#include <hip/hip_bf16.h>

typedef __bf16 bf16x8 __attribute__((ext_vector_type(8)));
typedef __bf16 bf16x4 __attribute__((ext_vector_type(4)));
typedef float  f32x4  __attribute__((ext_vector_type(4)));

#define MFMA16(a, b, c) __builtin_amdgcn_mfma_f32_16x16x32_bf16(a, b, c, 0, 0, 0)

__device__ __forceinline__ float lrelu(float v) { return fmaxf(v, 0.01f * v); }

// ---------------------------------------------------------------------------
// prep kernels
// ---------------------------------------------------------------------------

// w1s[f][h] = sum_i linear1_w[f][i][h]   (16384 elements)
__global__ void vg_w1s(const float* __restrict__ lw1, float* __restrict__ w1s) {
  int i = blockIdx.x * 256 + threadIdx.x;
  int f = i >> 6, h = i & 63;
  w1s[i] = lw1[f * 192 + h] + lw1[f * 192 + 64 + h] + lw1[f * 192 + 128 + h];
}

// W2T[f][n(16)][k(64)] = bf16(linear2_w[f][k][n&7])  -- rows 8..15 REPLICATE
__global__ void vg_w2t(const float* __restrict__ lw2, __bf16* __restrict__ w2t) {
  int i = blockIdx.x * 256 + threadIdx.x;
  int f = i >> 10, n = (i >> 6) & 15, k = i & 63;
  w2t[i] = (__bf16)lw2[(f * 64 + k) * 8 + (n & 7)];
}

// weffT[n(256)][f*8+k] = bf16( sum_d emb[f][k][d] * pw1[(f*128+d)*256 + n] )
// (algebraic collapse: W_eff = emb @ W1, K shrinks 32768 -> 2048)
__global__ void vg_weff(const float* __restrict__ emb, const float* __restrict__ pw1,
                        __bf16* __restrict__ weffT) {
  __shared__ float es[8][128];
  const int f = blockIdx.x, n = threadIdx.x;
  for (int i = n; i < 1024; i += 256) es[i >> 7][i & 127] = emb[f * 1024 + i];
  __syncthreads();
  float s[8] = {0.f, 0.f, 0.f, 0.f, 0.f, 0.f, 0.f, 0.f};
  const float* pp = pw1 + (size_t)f * 128 * 256 + n;
#pragma unroll 4
  for (int d = 0; d < 128; d++) {
    float wv = pp[(size_t)d * 256];
#pragma unroll
    for (int k = 0; k < 8; k++) s[k] += es[k][d] * wv;
  }
  bf16x8 o;
#pragma unroll
  for (int k = 0; k < 8; k++) o[k] = (__bf16)s[k];
  *(bf16x8*)&weffT[(size_t)n * 2048 + f * 8] = o;
}

// transpose [R][C] f32 -> [C][R] bf16, 64x64 LDS tiles (for proj_w2)
__global__ void vg_transpose(const float* __restrict__ in, __bf16* __restrict__ outT,
                             int R, int C) {
  __shared__ float tile[64][65];
  int tilesPerRow = C >> 6;
  int tr = blockIdx.x / tilesPerRow, tc = blockIdx.x % tilesPerRow;
  int r0 = tr * 64, c0 = tc * 64;
  int t = threadIdx.x;
  int cc = t & 63, rq = t >> 6;
#pragma unroll 4
  for (int i = 0; i < 16; i++) {
    int rr = rq * 16 + i;
    tile[rr][cc] = in[(size_t)(r0 + rr) * C + c0 + cc];
  }
  __syncthreads();
  int rr2 = t & 63, cq = t >> 6;
#pragma unroll 4
  for (int i = 0; i < 16; i++) {
    int cc2 = cq * 16 + i;
    outT[(size_t)(c0 + cc2) * R + r0 + rr2] = (__bf16)tile[rr2][cc2];
  }
}

// ---------------------------------------------------------------------------
// main fused kernel: grid = 64 row-tiles x 8 f-groups, 256 thr (4 waves).
// Wave owns 16 rows. Per f-quad: 4 gacc chains, then LOCKSTEP 4-wide softmax
// (pipelined shfls), packed-bf16 partner exchange, then 16 MFMA vs weffT.
// ---------------------------------------------------------------------------
__global__ __launch_bounds__(256, 2) void vg_main(
    const float* __restrict__ x,      // [4096][256]
    const float* __restrict__ w1s,    // [256][64]
    const float* __restrict__ b1,     // [256][64]
    const __bf16* __restrict__ w2t,   // [256][16][64] (rows 8-15 replicas)
    const float* __restrict__ b2l,    // [256][8]
    const float* __restrict__ tau,    // [256][8]
    const __bf16* __restrict__ weffT, // [256 n][2048 k]  k = f*8+bucket
    float* __restrict__ zpart)        // [8][4096][256]
{
  __shared__ __align__(16) float xs[64][36];  // 36: float4-aligned rows
  __shared__ __align__(16) float ws1[2048], wb1[2048];
  __shared__ __align__(16) float wb2[256], wtau[256];

  const int g = blockIdx.x & 7;          // f-group == XCD pin
  const int r0 = (blockIdx.x >> 3) * 64;
  const int f0 = g * 32;
  const int t = threadIdx.x;
  const int w = t >> 6, l = t & 63, lo = l & 15, hi = l >> 4;

  for (int i = t; i < 2048; i += 256) {
    int rr = i >> 5, cc = i & 31;
    float v = x[(size_t)(r0 + rr) * 256 + f0 + cc];
    v = (v != v) ? 0.f : v;
    xs[rr][cc] = fminf(fmaxf(v, 0.f), 65536.f);
    ws1[i] = w1s[f0 * 64 + i];
    wb1[i] = b1[f0 * 64 + i];
  }
  wb2[t] = b2l[f0 * 8 + t];
  wtau[t] = tau[f0 * 8 + t];
  __syncthreads();  // only barrier (r3 lesson)

  const int row = w * 16 + lo;

  // ---- produce paq for f-quad fq: lane hi keeps f=f0+fq*4+hi's 8 buckets
  auto produce = [&](int fq) -> bf16x8 {
    const float4 xq = *(const float4*)&xs[row][fq * 4];  // 4 subs' x in one read
    const float xr4[4] = {xq.x, xq.y, xq.z, xq.w};

    // A) 4 independent gacc chains (phase 1+2)
    f32x4 gb4[4];
#pragma unroll
    for (int sub = 0; sub < 4; sub++) {
      const int fi = fq * 4 + sub;
      const int f = f0 + fi;
      const float xr = xr4[sub];
      bf16x8 ha[2];
#pragma unroll
      for (int s = 0; s < 2; s++) {
        float4 wa = *(const float4*)(ws1 + fi * 64 + s * 32 + hi * 8);
        float4 wb = *(const float4*)(ws1 + fi * 64 + s * 32 + hi * 8 + 4);
        float4 ba = *(const float4*)(wb1 + fi * 64 + s * 32 + hi * 8);
        float4 bb = *(const float4*)(wb1 + fi * 64 + s * 32 + hi * 8 + 4);
        float hv[8];
        hv[0] = lrelu(xr * wa.x + ba.x);
        hv[1] = lrelu(xr * wa.y + ba.y);
        hv[2] = lrelu(xr * wa.z + ba.z);
        hv[3] = lrelu(xr * wa.w + ba.w);
        hv[4] = lrelu(xr * wb.x + bb.x);
        hv[5] = lrelu(xr * wb.y + bb.y);
        hv[6] = lrelu(xr * wb.z + bb.z);
        hv[7] = lrelu(xr * wb.w + bb.w);
#pragma unroll
        for (int j = 0; j < 8; j++) ha[s][j] = (__bf16)hv[j];
      }
      f32x4 gacc = {0.f, 0.f, 0.f, 0.f};
#pragma unroll
      for (int s = 0; s < 2; s++) {
        bf16x8 bw = *(const bf16x8*)&w2t[(f * 16 + lo) * 64 + s * 32 + hi * 8];
        gacc = MFMA16(bw, ha[s], gacc);
      }
      const int bidx = fi * 8 + (hi & 1) * 4;
      float4 b2v = *(const float4*)&wb2[bidx];
      float4 tv = *(const float4*)&wtau[bidx];
#pragma unroll
      for (int r = 0; r < 4; r++) gb4[sub][r] = lrelu(gacc[r] + b2v[r]) * tv[r];
    }

    // B) lockstep softmax: 4 independent chains, shfls pipelined 4-deep
    float m01[4];
#pragma unroll
    for (int sub = 0; sub < 4; sub++)
      m01[sub] = fmaxf(fmaxf(gb4[sub][0], gb4[sub][1]),
                       fmaxf(gb4[sub][2], gb4[sub][3]));
    float mx[4];
#pragma unroll
    for (int sub = 0; sub < 4; sub++)
      mx[sub] = fmaxf(m01[sub], __shfl_xor(m01[sub], 16));
    f32x4 ev4[4];
    float s4[4];
#pragma unroll
    for (int sub = 0; sub < 4; sub++) {
#pragma unroll
      for (int r = 0; r < 4; r++) ev4[sub][r] = __expf(gb4[sub][r] - mx[sub]);
      s4[sub] = (ev4[sub][0] + ev4[sub][1]) + (ev4[sub][2] + ev4[sub][3]);
    }
#pragma unroll
    for (int sub = 0; sub < 4; sub++) s4[sub] += __shfl_xor(s4[sub], 16);
    uint2 mineU[4];
#pragma unroll
    for (int sub = 0; sub < 4; sub++) {
      float inv = __builtin_amdgcn_rcpf(s4[sub]);
      bf16x4 p4;
#pragma unroll
      for (int r = 0; r < 4; r++) p4[r] = (__bf16)(ev4[sub][r] * inv);
      mineU[sub] = *(uint2*)&p4;
    }
    uint2 othU[4];
#pragma unroll
    for (int sub = 0; sub < 4; sub++) {
      othU[sub].x = __shfl_xor((int)mineU[sub].x, 16);
      othU[sub].y = __shfl_xor((int)mineU[sub].y, 16);
    }
    // C) assemble full8 per sub (bucket order 0..7 via parity), select hi's f
    bf16x8 paq = {};
#pragma unroll
    for (int sub = 0; sub < 4; sub++) {
      uint2 loU = (hi & 1) ? othU[sub] : mineU[sub];   // buckets 0..3
      uint2 hiU = (hi & 1) ? mineU[sub] : othU[sub];   // buckets 4..7
      bf16x8 f8;
      *(uint2*)&f8 = loU;
      *((uint2*)&f8 + 1) = hiU;
      if (hi == sub) paq = f8;
    }
    return paq;
  };

  f32x4 acc[16] = {};
  bf16x8 paq = produce(0);

  for (int fq = 0; fq < 8; fq++) {
    // issue B loads (independent of paq chain -> hoisted, L2 latency covered
    // by the next produce)
    const __bf16* bp = weffT + (size_t)(f0 + fq * 4) * 8 + hi * 8;
    bf16x8 Bq[16];
#pragma unroll
    for (int n = 0; n < 16; n++)
      Bq[n] = *(const bf16x8*)&bp[(size_t)(n * 16 + lo) * 2048];

    bf16x8 paq_next = {};
    if (fq < 7) paq_next = produce(fq + 1);

#pragma unroll
    for (int n = 0; n < 16; n++) acc[n] = MFMA16(paq, Bq[n], acc[n]);
    paq = paq_next;
  }

  // write zpart: wave's 16 rows x 256 cols
  float* zp = zpart + (size_t)g * (4096 * 256) + (size_t)(r0 + w * 16) * 256;
#pragma unroll
  for (int n = 0; n < 16; n++)
#pragma unroll
    for (int r = 0; r < 4; r++)
      zp[(hi * 4 + r) * 256 + n * 16 + lo] = acc[n][r];
}

// ---------------------------------------------------------------------------
// z[b][n] = bf16(relu(sum_g zpart + b1p[n]))  (x4 vectorized)
// ---------------------------------------------------------------------------
__global__ void vg_zred(const float* __restrict__ zpart, const float* __restrict__ b1p,
                        __bf16* __restrict__ z) {
  int i4 = (blockIdx.x * 256 + threadIdx.x) * 4;  // 1048576 total
  float4 s = *(const float4*)&b1p[i4 & 255];
#pragma unroll
  for (int g = 0; g < 8; g++) {
    float4 v = *(const float4*)&zpart[(size_t)g * 1048576 + i4];
    s.x += v.x; s.y += v.y; s.z += v.z; s.w += v.w;
  }
  bf16x4 o;
  o[0] = (__bf16)fmaxf(s.x, 0.f);
  o[1] = (__bf16)fmaxf(s.y, 0.f);
  o[2] = (__bf16)fmaxf(s.z, 0.f);
  o[3] = (__bf16)fmaxf(s.w, 0.f);
  *(bf16x4*)&z[i4] = o;
}

// ---------------------------------------------------------------------------
// out = z @ W2 + b2   (M=4096, N=4096, K=256)
// ---------------------------------------------------------------------------
__global__ __launch_bounds__(256, 2) void vg_out(
    const __bf16* __restrict__ z,    // [4096][256]
    const __bf16* __restrict__ w2t,  // [4096][256]  (W2T[n][k])
    const float* __restrict__ b2,    // [4096]
    float* __restrict__ out)         // [4096][4096]
{
  const int m0 = (blockIdx.x & 31) * 128;
  const int n0 = (blockIdx.x >> 5) * 128;
  const int t = threadIdx.x, w = t >> 6, l = t & 63, lo = l & 15, hi = l >> 4;
  const int wm = w >> 1, wn = w & 1;  // 2x2 waves, 64x64 each
  f32x4 acc[4][4] = {};
#pragma unroll
  for (int ks = 0; ks < 8; ks++) {
    bf16x8 A[4], Bq[4];
#pragma unroll
    for (int m = 0; m < 4; m++)
      A[m] = *(const bf16x8*)&z[(size_t)(m0 + wm * 64 + m * 16 + lo) * 256 + ks * 32 + hi * 8];
#pragma unroll
    for (int n = 0; n < 4; n++)
      Bq[n] = *(const bf16x8*)&w2t[(size_t)(n0 + wn * 64 + n * 16 + lo) * 256 + ks * 32 + hi * 8];
#pragma unroll
    for (int m = 0; m < 4; m++)
#pragma unroll
      for (int n = 0; n < 4; n++) acc[m][n] = MFMA16(A[m], Bq[n], acc[m][n]);
  }
#pragma unroll
  for (int m = 0; m < 4; m++)
#pragma unroll
    for (int n = 0; n < 4; n++) {
      int col = n0 + wn * 64 + n * 16 + lo;
      float bv = b2[col];
#pragma unroll
      for (int r = 0; r < 4; r++) {
        int row = m0 + wm * 64 + m * 16 + hi * 4 + r;
        out[(size_t)row * 4096 + col] = acc[m][n][r] + bv;
      }
    }
}

// ---------------------------------------------------------------------------
extern "C" void kernel_launch(void* const* d_in, const int* in_sizes, int n_in,
                              void* d_out, int out_size, void* d_ws, size_t ws_size,
                              hipStream_t stream) {
  const float* x   = (const float*)d_in[0];
  const float* lw1 = (const float*)d_in[1];
  const float* b1  = (const float*)d_in[2];
  const float* lw2 = (const float*)d_in[3];
  const float* b2l = (const float*)d_in[4];
  const float* tau = (const float*)d_in[5];
  const float* emb = (const float*)d_in[6];
  const float* pw1 = (const float*)d_in[7];
  const float* pb1 = (const float*)d_in[8];
  const float* pw2 = (const float*)d_in[9];
  const float* pb2 = (const float*)d_in[10];
  float* out = (float*)d_out;

  char* ws = (char*)d_ws;
  float*  w1s   = (float*)(ws + 0);         //   65536 B
  __bf16* w2t   = (__bf16*)(ws + 65536);    //  524288 B
  __bf16* weffT = (__bf16*)(ws + 589824);   // 1048576 B
  __bf16* w2t3  = (__bf16*)(ws + 1638400);  // 2097152 B
  __bf16* z     = (__bf16*)(ws + 3735552);  // 2097152 B
  float*  zpart = (float*)(ws + 5832704);   // 33554432 B (end ~39.4 MB)

  vg_w1s<<<64, 256, 0, stream>>>(lw1, w1s);
  vg_w2t<<<1024, 256, 0, stream>>>(lw2, w2t);
  vg_weff<<<256, 256, 0, stream>>>(emb, pw1, weffT);
  vg_transpose<<<256, 256, 0, stream>>>(pw2, w2t3, 256, 4096);
  vg_main<<<512, 256, 0, stream>>>(x, w1s, b1, w2t, b2l, tau, weffT, zpart);
  vg_zred<<<1024, 256, 0, stream>>>(zpart, pb1, z);
  vg_out<<<1024, 256, 0, stream>>>(z, w2t3, pb2, out);
}